// Round 1
// 321.468 us; speedup vs baseline: 1.0693x; 1.0693x over previous
//
#include <hip/hip_runtime.h>
#include <hip/hip_bf16.h>
#include <stdint.h>
#include <math.h>

#define NODES 8192
#define EDGES 4096
#define DIM   128
#define HID   256
#define NHEADS 4

using bf8   = __attribute__((ext_vector_type(8))) short;
using f32x4 = __attribute__((ext_vector_type(4))) float;
using i32x4 = __attribute__((ext_vector_type(4))) int;
using s16x4 = __attribute__((ext_vector_type(4))) short;

__device__ __forceinline__ short f2bf(float f) {
    uint32_t u = __float_as_uint(f);
    u += 0x7fffu + ((u >> 16) & 1u);   // RNE
    return (short)(u >> 16);
}
__device__ __forceinline__ float bf2f(short s) {
    return __uint_as_float(((uint32_t)(unsigned short)s) << 16);
}
// order-preserving float<->uint key for atomic min/max
__device__ __forceinline__ unsigned fkey(float f) {
    unsigned u = __float_as_uint(f);
    return (u & 0x80000000u) ? ~u : (u | 0x80000000u);
}
__device__ __forceinline__ float fdec(unsigned k) {
    unsigned u = (k & 0x80000000u) ? (k & 0x7fffffffu) : ~k;
    return __uint_as_float(u);
}
__device__ __forceinline__ bf8 pack8(f32x4 a, f32x4 b) {
    bf8 r;
#pragma unroll
    for (int j = 0; j < 4; ++j) { r[j] = f2bf(a[j]); r[4 + j] = f2bf(b[j]); }
    return r;
}

// Fragment-swizzled operand layout for 16x16x32 MFMA (B operand only now):
//   buf[(tile16 * 128 + chunk32) * 512 + lane * 8 .. +7]  (shorts)
// where lane = q*16 + r holds elems [col = tile*16 + r][k = chunk*32 + q*8 + j].
// The A operand (incidence) is consumed directly from f32 global memory in
// k_pgemm: lane l's 8 fragment elements are 8 CONTIGUOUS f32 in one row, so
// the "swizzle" is just an address computation + on-the-fly f2bf.

// ============ k_init: ef->swizzled bf16, x->bf16, fused weights/vectors,
// ============         amin/amax init (incidence handling moved to k_pgemm) ============
__global__ __launch_bounds__(256) void k_init(
        const float* __restrict__ ef, short* __restrict__ efB,
        const float* __restrict__ xf, short* __restrict__ xb,
        const float* __restrict__ Wn, const float* __restrict__ We, const float* __restrict__ Wo,
        const float* __restrict__ Wa, const float* __restrict__ bn, const float* __restrict__ be,
        const float* __restrict__ ba, const float* __restrict__ bo,
        short* __restrict__ A1T, short* __restrict__ A2T,
        float* __restrict__ v1, float* __restrict__ v2,
        float* __restrict__ u1, float* __restrict__ u2, float* __restrict__ cc,
        unsigned* __restrict__ amin, unsigned* __restrict__ amax) {
    __shared__ __align__(16) char smem[17408];
    int b = blockIdx.x, t = threadIdx.x;

    // ---- (1) blocks 0..127: build swizzled efB from ef [4096][128] ----
    if (b < 128) {
        float (*lb)[132] = (float(*)[132])smem;
        int k0 = b * 32;
#pragma unroll
        for (int i = 0; i < 4; ++i) {
            int idx4 = t + i * 256;
            int kk = idx4 >> 5, nq = idx4 & 31;
            f32x4 v = *(const f32x4*)&ef[(size_t)(k0 + kk) * DIM + nq * 4];
            lb[kk][nq * 4 + 0] = v[0]; lb[kk][nq * 4 + 1] = v[1];
            lb[kk][nq * 4 + 2] = v[2]; lb[kk][nq * 4 + 3] = v[3];
        }
        __syncthreads();
#pragma unroll
        for (int i = 0; i < 2; ++i) {
            int o = t + i * 256;
            int nt = o >> 6, lane = o & 63, nr = lane & 15, q = lane >> 4;
            bf8 pk;
#pragma unroll
            for (int j = 0; j < 8; ++j) pk[j] = f2bf(lb[q * 8 + j][nt * 16 + nr]);
            *(bf8*)&efB[((size_t)nt * 128 + b) * 512 + lane * 8] = pk;
        }
    }

    // ---- (2) all blocks: node_features f32 -> bf16 ----
#pragma unroll
    for (int i = 0; i < 2; ++i) {
        int idx = b * 256 + t + i * 131072;
        f32x4 v = *((const f32x4*)xf + idx);
        s16x4 o;
#pragma unroll
        for (int j = 0; j < 4; ++j) o[j] = f2bf(v[j]);
        *((s16x4*)xb + idx) = o;
    }
    // ---- (3) amin/amax init ----
    if (b == 511) {
#pragma unroll
        for (int i = 0; i < 2; ++i) {
            int u = t + i * 256;
            amin[u] = 0xFFFFFFFFu;
            amax[u] = 0u;
        }
    }

    // ---- (4) blocks 128..383: fused weights A1T=(Wn@Wo)^T, A2T=(We@Wo)^T ----
    if (b >= 128 && b < 384) {
        float (*lw)[128][17] = (float(*)[128][17])smem;
        int bb = b - 128;
        int h = bb >> 6, jj = bb & 63;
        int mat = t >> 7, k = t & 127;
        const float* WoH = Wo + (size_t)h * HID * DIM;
        float acc0 = 0.f, acc1 = 0.f;
        for (int mc = 0; mc < 16; ++mc) {
            __syncthreads();
#pragma unroll
            for (int i = 0; i < 4; ++i) {
                int u = t + i * 256;
                int m_ = u >> 9, kk2 = (u >> 2) & 127, qd = u & 3;
                const float* src = (m_ ? We : Wn) + (size_t)h * DIM * HID + (size_t)kk2 * HID + mc * 16 + qd * 4;
                f32x4 val = *(const f32x4*)src;
#pragma unroll
                for (int j2 = 0; j2 < 4; ++j2) lw[m_][kk2][qd * 4 + j2] = val[j2];
            }
            __syncthreads();
#pragma unroll
            for (int mm = 0; mm < 16; ++mm) {
                float a = lw[mat][k][mm];
                int m = mc * 16 + mm;
                acc0 += a * WoH[(size_t)m * DIM + jj];
                acc1 += a * WoH[(size_t)m * DIM + jj + 64];
            }
        }
        short* dst = mat ? A2T : A1T;
        dst[(size_t)h * DIM * DIM + (size_t)jj * DIM + k] = f2bf(acc0);
        dst[(size_t)h * DIM * DIM + (size_t)(jj + 64) * DIM + k] = f2bf(acc1);
    } else if (b >= 384 && b < 388) {
        // ---- (5) fused vectors for head h ----
        float (*lw)[128][17] = (float(*)[128][17])smem;
        int h = b - 384;
        int mat = t >> 7, k = t & 127;
        const float* wa = Wa + (size_t)h * HID;
        float acc = 0.f;
        for (int mc = 0; mc < 16; ++mc) {
            __syncthreads();
#pragma unroll
            for (int i = 0; i < 4; ++i) {
                int u = t + i * 256;
                int m_ = u >> 9, kk2 = (u >> 2) & 127, qd = u & 3;
                const float* src = (m_ ? We : Wn) + (size_t)h * DIM * HID + (size_t)kk2 * HID + mc * 16 + qd * 4;
                f32x4 val = *(const f32x4*)src;
#pragma unroll
                for (int j2 = 0; j2 < 4; ++j2) lw[m_][kk2][qd * 4 + j2] = val[j2];
            }
            __syncthreads();
#pragma unroll
            for (int mm = 0; mm < 16; ++mm) acc += lw[mat][k][mm] * wa[mc * 16 + mm];
        }
        (mat ? v2 : v1)[h * DIM + k] = acc;
        const float* bias = (mat ? be : bn) + (size_t)h * HID;
        const float* WoH = Wo + (size_t)h * HID * DIM;
        float ua = 0.f;
        for (int m = 0; m < HID; ++m) ua += bias[m] * WoH[(size_t)m * DIM + k];
        if (mat) u2[h * DIM + k] = ua;
        else     u1[h * DIM + k] = ua + bo[h * DIM + k];
        if (t < 64) {
            float c = 0.f;
#pragma unroll
            for (int j = 0; j < 4; ++j) { int m = t + j * 64; c += bn[(size_t)h * HID + m] * wa[m]; }
#pragma unroll
            for (int off = 1; off < 64; off <<= 1) c += __shfl_xor(c, off);
            if (t == 0) cc[h * 2 + 0] = c + ba[h];
        } else if (t < 128) {
            int l2 = t - 64;
            float c = 0.f;
#pragma unroll
            for (int j = 0; j < 4; ++j) { int m = l2 + j * 64; c += be[(size_t)h * HID + m] * wa[m]; }
#pragma unroll
            for (int off = 1; off < 64; off <<= 1) c += __shfl_xor(c, off);
            if (l2 == 0) cc[h * 2 + 1] = c;
        }
    }
}

// ============ k_pgemm: P = incidence @ ef, reading RAW f32 incidence ============
// 512 blocks = 256 Mtiles(32 rows) x K-split 2; 4 waves each own K=512 (16 chunks).
// A-fragment: lane l = q*16+r needs inc[row = m0+f*16+r][k = chunk*32 + q*8 + 0..7]
// = 8 contiguous f32 -> 2x dwordx4 + 8x f2bf. No LDS staging, no incB copy.
// Row-degree sums computed for free (every element passes through here exactly
// once); deterministic per-(ksplit,wave) partials -> rsp[8][NODES].
__global__ __launch_bounds__(256) void k_pgemm(const float* __restrict__ inc,
        const short* __restrict__ efB, float* __restrict__ Ppart, float* __restrict__ rsp) {
    __shared__ float red[2][32][129];
    const int t = threadIdx.x;
    const int w = t >> 6, l = t & 63, q = l >> 4, lr = l & 15;
    const int ms = blockIdx.x >> 1, ks = blockIdx.x & 1;
    const int m0 = ms * 32;
    const int c0 = ks * 64 + w * 16;
    const float* ap0 = inc + (size_t)(m0 + lr) * EDGES + (size_t)c0 * 32 + q * 8;
    const float* ap1 = ap0 + (size_t)16 * EDGES;
    const short*  bp = efB + (size_t)c0 * 512 + l * 8;

    f32x4 acc[2][8];
#pragma unroll
    for (int f = 0; f < 2; ++f)
#pragma unroll
        for (int cb = 0; cb < 8; ++cb) acc[f][cb] = (f32x4){0.f, 0.f, 0.f, 0.f};
    f32x4 rv0 = {0.f, 0.f, 0.f, 0.f}, rv1 = {0.f, 0.f, 0.f, 0.f};

    f32x4 xA0, xA1, yA0, yA1, xB0, xB1, yB0, yB1;
    bf8 bA[8], bB[8];
    xA0 = *(const f32x4*)ap0;       xA1 = *(const f32x4*)(ap0 + 4);
    yA0 = *(const f32x4*)ap1;       yA1 = *(const f32x4*)(ap1 + 4);
#pragma unroll
    for (int cb = 0; cb < 8; ++cb) bA[cb] = *(const bf8*)(bp + (size_t)cb * 65536);

    for (int s = 0; s < 16; s += 2) {
        // prefetch chunk s+1
        xB0 = *(const f32x4*)(ap0 + (s + 1) * 32); xB1 = *(const f32x4*)(ap0 + (s + 1) * 32 + 4);
        yB0 = *(const f32x4*)(ap1 + (s + 1) * 32); yB1 = *(const f32x4*)(ap1 + (s + 1) * 32 + 4);
#pragma unroll
        for (int cb = 0; cb < 8; ++cb) bB[cb] = *(const bf8*)(bp + (size_t)cb * 65536 + (s + 1) * 512);
        rv0 += xA0; rv0 += xA1; rv1 += yA0; rv1 += yA1;
        {
            bf8 a0 = pack8(xA0, xA1), a1 = pack8(yA0, yA1);
#pragma unroll
            for (int cb = 0; cb < 8; ++cb) {
                acc[0][cb] = __builtin_amdgcn_mfma_f32_16x16x32_bf16(a0, bA[cb], acc[0][cb], 0, 0, 0);
                acc[1][cb] = __builtin_amdgcn_mfma_f32_16x16x32_bf16(a1, bA[cb], acc[1][cb], 0, 0, 0);
            }
        }
        // prefetch chunk s+2
        if (s + 2 < 16) {
            xA0 = *(const f32x4*)(ap0 + (s + 2) * 32); xA1 = *(const f32x4*)(ap0 + (s + 2) * 32 + 4);
            yA0 = *(const f32x4*)(ap1 + (s + 2) * 32); yA1 = *(const f32x4*)(ap1 + (s + 2) * 32 + 4);
#pragma unroll
            for (int cb = 0; cb < 8; ++cb) bA[cb] = *(const bf8*)(bp + (size_t)cb * 65536 + (s + 2) * 512);
        }
        rv0 += xB0; rv0 += xB1; rv1 += yB0; rv1 += yB1;
        {
            bf8 a0 = pack8(xB0, xB1), a1 = pack8(yB0, yB1);
#pragma unroll
            for (int cb = 0; cb < 8; ++cb) {
                acc[0][cb] = __builtin_amdgcn_mfma_f32_16x16x32_bf16(a0, bB[cb], acc[0][cb], 0, 0, 0);
                acc[1][cb] = __builtin_amdgcn_mfma_f32_16x16x32_bf16(a1, bB[cb], acc[1][cb], 0, 0, 0);
            }
        }
    }

    // row-degree partial sums: reduce over q (lanes lr, lr+16, lr+32, lr+48)
    float rs0 = rv0[0] + rv0[1] + rv0[2] + rv0[3];
    float rs1 = rv1[0] + rv1[1] + rv1[2] + rv1[3];
    rs0 += __shfl_xor(rs0, 16); rs0 += __shfl_xor(rs0, 32);
    rs1 += __shfl_xor(rs1, 16); rs1 += __shfl_xor(rs1, 32);
    if (l < 16) {
        float* rp = rsp + (size_t)(ks * 4 + w) * NODES + m0;
        rp[lr] = rs0;
        rp[16 + lr] = rs1;
    }

    // cross-wave reduce (waves 0+2 -> red[0], 1+3 -> red[1])
    if (w < 2) {
#pragma unroll
        for (int f = 0; f < 2; ++f)
#pragma unroll
            for (int cb = 0; cb < 8; ++cb)
#pragma unroll
                for (int r = 0; r < 4; ++r)
                    red[w][f * 16 + q * 4 + r][cb * 16 + lr] = acc[f][cb][r];
    }
    __syncthreads();
    if (w >= 2) {
#pragma unroll
        for (int f = 0; f < 2; ++f)
#pragma unroll
            for (int cb = 0; cb < 8; ++cb)
#pragma unroll
                for (int r = 0; r < 4; ++r)
                    red[w - 2][f * 16 + q * 4 + r][cb * 16 + lr] += acc[f][cb][r];
    }
    __syncthreads();
    float* gp = Ppart + (size_t)ks * (NODES * DIM) + (size_t)m0 * DIM;
#pragma unroll
    for (int i = 0; i < 4; ++i) {
        int idx = t + i * 256;
        int row = idx >> 5, c4 = (idx & 31) * 4;
        f32x4 o;
#pragma unroll
        for (int j = 0; j < 4; ++j) o[j] = red[0][row][c4 + j] + red[1][row][c4 + j];
        *(f32x4*)&gp[(size_t)row * DIM + c4] = o;
    }
}

// ============ k_comb: Pbf = bf16(Ppart0 + Ppart1); rs = sum of 8 rsp parts ============
__global__ __launch_bounds__(256) void k_comb(const float* __restrict__ Ppart, short* __restrict__ Pbf,
        const float* __restrict__ rsp, float* __restrict__ rs) {
    int idx = blockIdx.x * 256 + threadIdx.x;   // 262144 f32x4
    if (blockIdx.x < 32) {
        float s = 0.f;
#pragma unroll
        for (int p = 0; p < 8; ++p) s += rsp[(size_t)p * NODES + idx];
        rs[idx] = s;
    }
    f32x4 a = *((const f32x4*)Ppart + idx);
    f32x4 b = *((const f32x4*)Ppart + 262144 + idx);
    s16x4 o;
#pragma unroll
    for (int j = 0; j < 4; ++j) o[j] = f2bf(a[j] + b[j]);
    *((s16x4*)Pbf + idx) = o;
}

// ============ k_out: per-head fused normalize-in + score + GEMM + atomic minmax ============
__global__ __launch_bounds__(256) void k_out(
        const short* __restrict__ xb,      // head 0 input (bf16) or nullptr
        const float* xf,                   // heads>=1: prev outp f32 (aliases outw)
        const unsigned* __restrict__ aminP, const unsigned* __restrict__ amaxP,
        const short* __restrict__ Pbf, const float* __restrict__ rs,
        const short* __restrict__ W1, const short* __restrict__ W2,
        const float* __restrict__ v1, const float* __restrict__ v2,
        const float* __restrict__ cc, const float* __restrict__ u1, const float* __restrict__ u2,
        unsigned* __restrict__ aminC, unsigned* __restrict__ amaxC,
        float* outw) {
    __shared__ short lx[16][136];
    __shared__ short lp[16][136];
    __shared__ float sv1[128], sv2[128], rsL[16], idL[16], coL[16];
    int t = threadIdx.x, m0 = blockIdx.x * 16;
    int w = t >> 6, l = t & 63, q = l >> 4, lr = l & 15;
    bf8 b1[2][4], b2[2][4];
#pragma unroll
    for (int nf = 0; nf < 2; ++nf) {
        int n = w * 32 + nf * 16 + lr;
#pragma unroll
        for (int kk = 0; kk < 4; ++kk) {
            b1[nf][kk] = *(const bf8*)&W1[(size_t)n * DIM + kk * 32 + q * 8];
            b2[nf][kk] = *(const bf8*)&W2[(size_t)n * DIM + kk * 32 + q * 8];
        }
    }
    {
        int row = t >> 4, c = (t & 15) * 8;
        if (xb) {
            *(i32x4*)&lx[row][c] = *(const i32x4*)&xb[(size_t)(m0 + row) * DIM + c];
        } else {
            f32x4 x0 = *(const f32x4*)&xf[(size_t)(m0 + row) * DIM + c];
            f32x4 x1 = *(const f32x4*)&xf[(size_t)(m0 + row) * DIM + c + 4];
            bf8 pk;
#pragma unroll
            for (int j = 0; j < 8; ++j) {
                float mn = fdec(aminP[c + j]);
                float rv = 1.f / (fdec(amaxP[c + j]) - mn + 1e-8f);
                float xv = (j < 4) ? x0[j] : x1[j - 4];
                pk[j] = f2bf(fmaxf((xv - mn) * rv, 0.f));
            }
            *(bf8*)&lx[row][c] = pk;
        }
        *(i32x4*)&lp[row][c] = *(const i32x4*)&Pbf[(size_t)(m0 + row) * DIM + c];
    }
    if (t < 128) { sv1[t] = v1[t]; sv2[t] = v2[t]; }
    if (t < 16) { float r = rs[m0 + t]; rsL[t] = r; idL[t] = 1.f / (r + 1e-8f); }
    __syncthreads();
    if (t < 128) {
        int row = t >> 3, seg = t & 7;
        float id = idL[row];
        float s = 0.f;
#pragma unroll
        for (int j = 0; j < 16; ++j) {
            int c3 = seg * 16 + j;
            s += bf2f(lx[row][c3]) * sv1[c3] + bf2f(lp[row][c3]) * (sv2[c3] * id);
        }
        s += __shfl_xor(s, 1); s += __shfl_xor(s, 2); s += __shfl_xor(s, 4);
        if (seg == 0) {
            float sc = s + cc[0] + rsL[row] * cc[1] * id;
            sc = sc > 0.f ? sc : 0.2f * sc;
            coL[row] = 1.f / (1.f + __expf(-sc));
        }
    }
    f32x4 a1[2] = {{0.f, 0.f, 0.f, 0.f}, {0.f, 0.f, 0.f, 0.f}};
    f32x4 a2[2] = {{0.f, 0.f, 0.f, 0.f}, {0.f, 0.f, 0.f, 0.f}};
#pragma unroll
    for (int kk = 0; kk < 4; ++kk) {
        bf8 xa = *(bf8*)&lx[lr][kk * 32 + q * 8];
        bf8 pa = *(bf8*)&lp[lr][kk * 32 + q * 8];
#pragma unroll
        for (int nf = 0; nf < 2; ++nf) {
            a1[nf] = __builtin_amdgcn_mfma_f32_16x16x32_bf16(xa, b1[nf][kk], a1[nf], 0, 0, 0);
            a2[nf] = __builtin_amdgcn_mfma_f32_16x16x32_bf16(pa, b2[nf][kk], a2[nf], 0, 0, 0);
        }
    }
    __syncthreads();   // coL visible
#pragma unroll
    for (int nf = 0; nf < 2; ++nf) {
        int col = w * 32 + nf * 16 + lr;
        float u1v = u1[col], u2v = u2[col];
        float mnv = 1e30f, mxv = -1e30f;
#pragma unroll
        for (int r = 0; r < 4; ++r) {
            int row = q * 4 + r;
            float cf = coL[row] * idL[row];
            float v = a1[nf][r] + cf * a2[nf][r] + u1v + rsL[row] * cf * u2v;
            outw[(size_t)(m0 + row) * DIM + col] = v;
            mnv = fminf(mnv, v); mxv = fmaxf(mxv, v);
        }
        mnv = fminf(mnv, __shfl_xor(mnv, 16)); mnv = fminf(mnv, __shfl_xor(mnv, 32));
        mxv = fmaxf(mxv, __shfl_xor(mxv, 16)); mxv = fmaxf(mxv, __shfl_xor(mxv, 32));
        if (l < 16) {
            atomicMin(&aminC[col], fkey(mnv));
            atomicMax(&amaxC[col], fkey(mxv));
        }
    }
}

// ============ k_fin: decode last head's minmax, normalize + relu -> d_out ============
__global__ __launch_bounds__(256) void k_fin(const float* __restrict__ outp,
        const unsigned* __restrict__ amin, const unsigned* __restrict__ amax,
        float* __restrict__ dst) {
    __shared__ float smn[128], srv[128];
    int t = threadIdx.x;
    if (t < 128) {
        float mn = fdec(amin[t]);
        smn[t] = mn;
        srv[t] = 1.f / (fdec(amax[t]) - mn + 1e-8f);
    }
    __syncthreads();
#pragma unroll
    for (int i = 0; i < 2; ++i) {
        int idx = blockIdx.x * 256 + t + i * 131072;
        f32x4 v = *((const f32x4*)outp + idx);
        int c0 = (idx & 31) * 4;
#pragma unroll
        for (int j = 0; j < 4; ++j) v[j] = fmaxf((v[j] - smn[c0 + j]) * srv[c0 + j], 0.f);
        *((f32x4*)dst + idx) = v;
    }
}

extern "C" void kernel_launch(void* const* d_in, const int* in_sizes, int n_in,
                              void* d_out, int out_size, void* d_ws, size_t ws_size,
                              hipStream_t stream) {
    const float* nodef = (const float*)d_in[0];
    const float* inc   = (const float*)d_in[1];
    const float* ef    = (const float*)d_in[2];
    const float* Wn    = (const float*)d_in[3];
    const float* bn    = (const float*)d_in[4];
    const float* We    = (const float*)d_in[5];
    const float* be    = (const float*)d_in[6];
    const float* Wa    = (const float*)d_in[7];
    const float* ba    = (const float*)d_in[8];
    const float* Wo    = (const float*)d_in[9];
    const float* bo    = (const float*)d_in[10];

    char* ws = (char*)d_ws;
    float*    outp  = (float*)(ws);                 // 4 MB
    short*    Pbf   = (short*)(ws + 4194304);       // 2 MB
    short*    xb    = (short*)(ws + 6291456);       // 2 MB
    short*    efB   = (short*)(ws + 8388608);       // 1 MB (swizzled)
    float*    Ppart = (float*)(ws + 9437184);       // 8 MB (2 K-split parts)
    short*    A1T   = (short*)(ws + 17825792);      // 128 KB
    short*    A2T   = (short*)(ws + 17956864);      // 128 KB
    float*    rs    = (float*)(ws + 18087936);      // 32 KB
    float*    rsp   = (float*)(ws + 18120704);      // 256 KB (8 partials x 8192)
    float*    v1    = (float*)(ws + 18382848);
    float*    v2    = (float*)(ws + 18384896);
    float*    u1    = (float*)(ws + 18386944);
    float*    u2    = (float*)(ws + 18388992);
    float*    cc    = (float*)(ws + 18391040);
    unsigned* amin  = (unsigned*)(ws + 18393088);   // 4x128
    unsigned* amax  = (unsigned*)(ws + 18395136);   // 4x128

    hipLaunchKernelGGL(k_init, dim3(512), dim3(256), 0, stream,
                       ef, efB, nodef, xb, Wn, We, Wo, Wa, bn, be, ba, bo,
                       A1T, A2T, v1, v2, u1, u2, cc, amin, amax);
    hipLaunchKernelGGL(k_pgemm, dim3(512), dim3(256), 0, stream, inc, efB, Ppart, rsp);
    hipLaunchKernelGGL(k_comb, dim3(1024), dim3(256), 0, stream, Ppart, Pbf, rsp, rs);

    for (int h = 0; h < NHEADS; ++h) {
        hipLaunchKernelGGL(k_out, dim3(512), dim3(256), 0, stream,
                           (h == 0) ? xb : (const short*)nullptr,
                           (h == 0) ? (const float*)nullptr : outp,
                           (h == 0) ? (const unsigned*)nullptr : amin + (h - 1) * DIM,
                           (h == 0) ? (const unsigned*)nullptr : amax + (h - 1) * DIM,
                           Pbf, rs,
                           A1T + (size_t)h * DIM * DIM, A2T + (size_t)h * DIM * DIM,
                           v1 + h * DIM, v2 + h * DIM, cc + h * 2,
                           u1 + h * DIM, u2 + h * DIM,
                           amin + h * DIM, amax + h * DIM, outp);
    }
    hipLaunchKernelGGL(k_fin, dim3(512), dim3(256), 0, stream, outp,
                       amin + 3 * DIM, amax + 3 * DIM, (float*)d_out);
}

// Round 2
// 284.895 us; speedup vs baseline: 1.2066x; 1.1284x over previous
//
#include <hip/hip_runtime.h>
#include <hip/hip_bf16.h>
#include <stdint.h>
#include <math.h>

#define NODES 8192
#define EDGES 4096
#define DIM   128
#define HID   256
#define NHEADS 4
#define NSHADOW 8   // min/max shadow copies to cut atomic serialization

using bf8   = __attribute__((ext_vector_type(8))) short;
using f32x4 = __attribute__((ext_vector_type(4))) float;
using i32x4 = __attribute__((ext_vector_type(4))) int;
using s16x4 = __attribute__((ext_vector_type(4))) short;

__device__ __forceinline__ short f2bf(float f) {
    uint32_t u = __float_as_uint(f);
    u += 0x7fffu + ((u >> 16) & 1u);   // RNE
    return (short)(u >> 16);
}
__device__ __forceinline__ float bf2f(short s) {
    return __uint_as_float(((uint32_t)(unsigned short)s) << 16);
}
// order-preserving float<->uint key for atomic min/max
__device__ __forceinline__ unsigned fkey(float f) {
    unsigned u = __float_as_uint(f);
    return (u & 0x80000000u) ? ~u : (u | 0x80000000u);
}
__device__ __forceinline__ float fdec(unsigned k) {
    unsigned u = (k & 0x80000000u) ? (k & 0x7fffffffu) : ~k;
    return __uint_as_float(u);
}
__device__ __forceinline__ bf8 pack8(f32x4 a, f32x4 b) {
    bf8 r;
#pragma unroll
    for (int j = 0; j < 4; ++j) { r[j] = f2bf(a[j]); r[4 + j] = f2bf(b[j]); }
    return r;
}

// Fragment-swizzled operand layout for 16x16x32 MFMA (B operand only):
//   buf[(tile16 * 128 + chunk32) * 512 + lane * 8 .. +7]  (shorts)
// where lane = q*16 + r holds elems [col = tile*16 + r][k = chunk*32 + q*8 + j].
// The A operand (incidence) is consumed directly from f32 global memory in
// k_pgemm: lane l's 8 fragment elements are 8 CONTIGUOUS f32 in one row.

// ============ k_init: ef->swizzled bf16, x->bf16, fused weights/vectors,
// ============         shadow amin/amax init ============
__global__ __launch_bounds__(256) void k_init(
        const float* __restrict__ ef, short* __restrict__ efB,
        const float* __restrict__ xf, short* __restrict__ xb,
        const float* __restrict__ Wn, const float* __restrict__ We, const float* __restrict__ Wo,
        const float* __restrict__ Wa, const float* __restrict__ bn, const float* __restrict__ be,
        const float* __restrict__ ba, const float* __restrict__ bo,
        short* __restrict__ A1T, short* __restrict__ A2T,
        float* __restrict__ v1, float* __restrict__ v2,
        float* __restrict__ u1, float* __restrict__ u2, float* __restrict__ cc,
        unsigned* __restrict__ amin, unsigned* __restrict__ amax) {
    __shared__ __align__(16) char smem[17408];
    int b = blockIdx.x, t = threadIdx.x;

    // ---- (1) blocks 0..127: build swizzled efB from ef [4096][128] ----
    if (b < 128) {
        float (*lb)[132] = (float(*)[132])smem;
        int k0 = b * 32;
#pragma unroll
        for (int i = 0; i < 4; ++i) {
            int idx4 = t + i * 256;
            int kk = idx4 >> 5, nq = idx4 & 31;
            f32x4 v = *(const f32x4*)&ef[(size_t)(k0 + kk) * DIM + nq * 4];
            lb[kk][nq * 4 + 0] = v[0]; lb[kk][nq * 4 + 1] = v[1];
            lb[kk][nq * 4 + 2] = v[2]; lb[kk][nq * 4 + 3] = v[3];
        }
        __syncthreads();
#pragma unroll
        for (int i = 0; i < 2; ++i) {
            int o = t + i * 256;
            int nt = o >> 6, lane = o & 63, nr = lane & 15, q = lane >> 4;
            bf8 pk;
#pragma unroll
            for (int j = 0; j < 8; ++j) pk[j] = f2bf(lb[q * 8 + j][nt * 16 + nr]);
            *(bf8*)&efB[((size_t)nt * 128 + b) * 512 + lane * 8] = pk;
        }
    }

    // ---- (2) all blocks: node_features f32 -> bf16 ----
#pragma unroll
    for (int i = 0; i < 2; ++i) {
        int idx = b * 256 + t + i * 131072;
        f32x4 v = *((const f32x4*)xf + idx);
        s16x4 o;
#pragma unroll
        for (int j = 0; j < 4; ++j) o[j] = f2bf(v[j]);
        *((s16x4*)xb + idx) = o;
    }
    // ---- (3) shadow amin/amax init: NHEADS * NSHADOW * 128 = 4096 each ----
    if (b == 511) {
#pragma unroll
        for (int i = 0; i < 16; ++i) {
            int u = t + i * 256;
            amin[u] = 0xFFFFFFFFu;
            amax[u] = 0u;
        }
    }

    // ---- (4) blocks 128..383: fused weights A1T=(Wn@Wo)^T, A2T=(We@Wo)^T ----
    if (b >= 128 && b < 384) {
        float (*lw)[128][17] = (float(*)[128][17])smem;
        int bb = b - 128;
        int h = bb >> 6, jj = bb & 63;
        int mat = t >> 7, k = t & 127;
        const float* WoH = Wo + (size_t)h * HID * DIM;
        float acc0 = 0.f, acc1 = 0.f;
        for (int mc = 0; mc < 16; ++mc) {
            __syncthreads();
#pragma unroll
            for (int i = 0; i < 4; ++i) {
                int u = t + i * 256;
                int m_ = u >> 9, kk2 = (u >> 2) & 127, qd = u & 3;
                const float* src = (m_ ? We : Wn) + (size_t)h * DIM * HID + (size_t)kk2 * HID + mc * 16 + qd * 4;
                f32x4 val = *(const f32x4*)src;
#pragma unroll
                for (int j2 = 0; j2 < 4; ++j2) lw[m_][kk2][qd * 4 + j2] = val[j2];
            }
            __syncthreads();
#pragma unroll
            for (int mm = 0; mm < 16; ++mm) {
                float a = lw[mat][k][mm];
                int m = mc * 16 + mm;
                acc0 += a * WoH[(size_t)m * DIM + jj];
                acc1 += a * WoH[(size_t)m * DIM + jj + 64];
            }
        }
        short* dst = mat ? A2T : A1T;
        dst[(size_t)h * DIM * DIM + (size_t)jj * DIM + k] = f2bf(acc0);
        dst[(size_t)h * DIM * DIM + (size_t)(jj + 64) * DIM + k] = f2bf(acc1);
    } else if (b >= 384 && b < 388) {
        // ---- (5) fused vectors for head h ----
        float (*lw)[128][17] = (float(*)[128][17])smem;
        int h = b - 384;
        int mat = t >> 7, k = t & 127;
        const float* wa = Wa + (size_t)h * HID;
        float acc = 0.f;
        for (int mc = 0; mc < 16; ++mc) {
            __syncthreads();
#pragma unroll
            for (int i = 0; i < 4; ++i) {
                int u = t + i * 256;
                int m_ = u >> 9, kk2 = (u >> 2) & 127, qd = u & 3;
                const float* src = (m_ ? We : Wn) + (size_t)h * DIM * HID + (size_t)kk2 * HID + mc * 16 + qd * 4;
                f32x4 val = *(const f32x4*)src;
#pragma unroll
                for (int j2 = 0; j2 < 4; ++j2) lw[m_][kk2][qd * 4 + j2] = val[j2];
            }
            __syncthreads();
#pragma unroll
            for (int mm = 0; mm < 16; ++mm) acc += lw[mat][k][mm] * wa[mc * 16 + mm];
        }
        (mat ? v2 : v1)[h * DIM + k] = acc;
        const float* bias = (mat ? be : bn) + (size_t)h * HID;
        const float* WoH = Wo + (size_t)h * HID * DIM;
        float ua = 0.f;
        for (int m = 0; m < HID; ++m) ua += bias[m] * WoH[(size_t)m * DIM + k];
        if (mat) u2[h * DIM + k] = ua;
        else     u1[h * DIM + k] = ua + bo[h * DIM + k];
        if (t < 64) {
            float c = 0.f;
#pragma unroll
            for (int j = 0; j < 4; ++j) { int m = t + j * 64; c += bn[(size_t)h * HID + m] * wa[m]; }
#pragma unroll
            for (int off = 1; off < 64; off <<= 1) c += __shfl_xor(c, off);
            if (t == 0) cc[h * 2 + 0] = c + ba[h];
        } else if (t < 128) {
            int l2 = t - 64;
            float c = 0.f;
#pragma unroll
            for (int j = 0; j < 4; ++j) { int m = l2 + j * 64; c += be[(size_t)h * HID + m] * wa[m]; }
#pragma unroll
            for (int off = 1; off < 64; off <<= 1) c += __shfl_xor(c, off);
            if (l2 == 0) cc[h * 2 + 1] = c;
        }
    }
}

// ============ k_pgemm: Pbf = bf16(incidence @ ef), rs = rowsum(incidence) ============
// 256 blocks x 512 threads: 8 waves, wave w owns K-range [w*512, w*512+512).
// Full-K accumulation in-block (8-wave LDS tree) -> no Ppart round-trip, no k_comb.
__global__ __launch_bounds__(512) void k_pgemm(const float* __restrict__ inc,
        const short* __restrict__ efB, short* __restrict__ Pbf, float* __restrict__ rs) {
    __shared__ float red[2][32][129];
    __shared__ float rsr[8][32];
    const int t = threadIdx.x;
    const int w = t >> 6, l = t & 63, q = l >> 4, lr = l & 15;
    const int m0 = blockIdx.x * 32;
    const int c0 = w * 16;                       // first chunk (of 128) for this wave
    const float* ap0 = inc + (size_t)(m0 + lr) * EDGES + (size_t)c0 * 32 + q * 8;
    const float* ap1 = ap0 + (size_t)16 * EDGES;
    const short*  bp = efB + (size_t)c0 * 512 + l * 8;

    f32x4 acc[2][8];
#pragma unroll
    for (int f = 0; f < 2; ++f)
#pragma unroll
        for (int cb = 0; cb < 8; ++cb) acc[f][cb] = (f32x4){0.f, 0.f, 0.f, 0.f};
    f32x4 rv0 = {0.f, 0.f, 0.f, 0.f}, rv1 = {0.f, 0.f, 0.f, 0.f};

    f32x4 xA0, xA1, yA0, yA1, xB0, xB1, yB0, yB1;
    bf8 bA[8], bB[8];
    xA0 = *(const f32x4*)ap0;       xA1 = *(const f32x4*)(ap0 + 4);
    yA0 = *(const f32x4*)ap1;       yA1 = *(const f32x4*)(ap1 + 4);
#pragma unroll
    for (int cb = 0; cb < 8; ++cb) bA[cb] = *(const bf8*)(bp + (size_t)cb * 65536);

    for (int s = 0; s < 16; s += 2) {
        // prefetch chunk s+1
        xB0 = *(const f32x4*)(ap0 + (s + 1) * 32); xB1 = *(const f32x4*)(ap0 + (s + 1) * 32 + 4);
        yB0 = *(const f32x4*)(ap1 + (s + 1) * 32); yB1 = *(const f32x4*)(ap1 + (s + 1) * 32 + 4);
#pragma unroll
        for (int cb = 0; cb < 8; ++cb) bB[cb] = *(const bf8*)(bp + (size_t)cb * 65536 + (s + 1) * 512);
        rv0 += xA0; rv0 += xA1; rv1 += yA0; rv1 += yA1;
        {
            bf8 a0 = pack8(xA0, xA1), a1 = pack8(yA0, yA1);
#pragma unroll
            for (int cb = 0; cb < 8; ++cb) {
                acc[0][cb] = __builtin_amdgcn_mfma_f32_16x16x32_bf16(a0, bA[cb], acc[0][cb], 0, 0, 0);
                acc[1][cb] = __builtin_amdgcn_mfma_f32_16x16x32_bf16(a1, bA[cb], acc[1][cb], 0, 0, 0);
            }
        }
        // prefetch chunk s+2
        if (s + 2 < 16) {
            xA0 = *(const f32x4*)(ap0 + (s + 2) * 32); xA1 = *(const f32x4*)(ap0 + (s + 2) * 32 + 4);
            yA0 = *(const f32x4*)(ap1 + (s + 2) * 32); yA1 = *(const f32x4*)(ap1 + (s + 2) * 32 + 4);
#pragma unroll
            for (int cb = 0; cb < 8; ++cb) bA[cb] = *(const bf8*)(bp + (size_t)cb * 65536 + (s + 2) * 512);
        }
        rv0 += xB0; rv0 += xB1; rv1 += yB0; rv1 += yB1;
        {
            bf8 a0 = pack8(xB0, xB1), a1 = pack8(yB0, yB1);
#pragma unroll
            for (int cb = 0; cb < 8; ++cb) {
                acc[0][cb] = __builtin_amdgcn_mfma_f32_16x16x32_bf16(a0, bB[cb], acc[0][cb], 0, 0, 0);
                acc[1][cb] = __builtin_amdgcn_mfma_f32_16x16x32_bf16(a1, bB[cb], acc[1][cb], 0, 0, 0);
            }
        }
    }

    // row-degree partial sums: reduce over q (shfl 16/32), store per-wave partials
    float rs0 = rv0[0] + rv0[1] + rv0[2] + rv0[3];
    float rs1 = rv1[0] + rv1[1] + rv1[2] + rv1[3];
    rs0 += __shfl_xor(rs0, 16); rs0 += __shfl_xor(rs0, 32);
    rs1 += __shfl_xor(rs1, 16); rs1 += __shfl_xor(rs1, 32);
    if (l < 16) { rsr[w][lr] = rs0; rsr[w][16 + lr] = rs1; }

    // 8-wave accumulator reduce into red[0..1], then red[0]+red[1] at write
    if (w < 2) {
#pragma unroll
        for (int f = 0; f < 2; ++f)
#pragma unroll
            for (int cb = 0; cb < 8; ++cb)
#pragma unroll
                for (int r = 0; r < 4; ++r)
                    red[w][f * 16 + q * 4 + r][cb * 16 + lr] = acc[f][cb][r];
    }
    __syncthreads();
    if (w == 2 || w == 3) {
#pragma unroll
        for (int f = 0; f < 2; ++f)
#pragma unroll
            for (int cb = 0; cb < 8; ++cb)
#pragma unroll
                for (int r = 0; r < 4; ++r)
                    red[w - 2][f * 16 + q * 4 + r][cb * 16 + lr] += acc[f][cb][r];
    }
    __syncthreads();
    if (w == 4 || w == 5) {
#pragma unroll
        for (int f = 0; f < 2; ++f)
#pragma unroll
            for (int cb = 0; cb < 8; ++cb)
#pragma unroll
                for (int r = 0; r < 4; ++r)
                    red[w - 4][f * 16 + q * 4 + r][cb * 16 + lr] += acc[f][cb][r];
    }
    __syncthreads();
    if (w == 6 || w == 7) {
#pragma unroll
        for (int f = 0; f < 2; ++f)
#pragma unroll
            for (int cb = 0; cb < 8; ++cb)
#pragma unroll
                for (int r = 0; r < 4; ++r)
                    red[w - 6][f * 16 + q * 4 + r][cb * 16 + lr] += acc[f][cb][r];
    }
    __syncthreads();

    // write Pbf (bf16) directly
    {
        int row = t >> 4, c = (t & 15) * 8;
        bf8 pk;
#pragma unroll
        for (int j = 0; j < 8; ++j) pk[j] = f2bf(red[0][row][c + j] + red[1][row][c + j]);
        *(bf8*)&Pbf[(size_t)(m0 + row) * DIM + c] = pk;
    }
    // write rs
    if (t < 32) {
        float s = 0.f;
#pragma unroll
        for (int p = 0; p < 8; ++p) s += rsr[p][t];
        rs[m0 + t] = s;
    }
}

// ============ k_out: per-head fused normalize-in + score + GEMM + shadow minmax ============
__global__ __launch_bounds__(256) void k_out(
        const short* __restrict__ xb,      // head 0 input (bf16) or nullptr
        const float* xf,                   // heads>=1: prev outp f32 (aliases outw)
        const unsigned* __restrict__ aminP, const unsigned* __restrict__ amaxP, // [NSHADOW][128]
        const short* __restrict__ Pbf, const float* __restrict__ rs,
        const short* __restrict__ W1, const short* __restrict__ W2,
        const float* __restrict__ v1, const float* __restrict__ v2,
        const float* __restrict__ cc, const float* __restrict__ u1, const float* __restrict__ u2,
        unsigned* __restrict__ aminC, unsigned* __restrict__ amaxC,             // [NSHADOW][128]
        float* outw) {
    __shared__ short lx[16][136];
    __shared__ short lp[16][136];
    __shared__ float sv1[128], sv2[128], rsL[16], idL[16], coL[16];
    __shared__ float smn[128], srv[128];
    int t = threadIdx.x, m0 = blockIdx.x * 16;
    int w = t >> 6, l = t & 63, q = l >> 4, lr = l & 15;
    // reduce previous head's shadow min/max copies (heads >= 1)
    if (!xb) {
        if (t < 128) {
            unsigned kmn = 0xFFFFFFFFu, kmx = 0u;
#pragma unroll
            for (int p = 0; p < NSHADOW; ++p) {
                kmn = min(kmn, aminP[p * DIM + t]);
                kmx = max(kmx, amaxP[p * DIM + t]);
            }
            float mn = fdec(kmn);
            smn[t] = mn;
            srv[t] = 1.f / (fdec(kmx) - mn + 1e-8f);
        }
        __syncthreads();
    }
    bf8 b1[2][4], b2[2][4];
#pragma unroll
    for (int nf = 0; nf < 2; ++nf) {
        int n = w * 32 + nf * 16 + lr;
#pragma unroll
        for (int kk = 0; kk < 4; ++kk) {
            b1[nf][kk] = *(const bf8*)&W1[(size_t)n * DIM + kk * 32 + q * 8];
            b2[nf][kk] = *(const bf8*)&W2[(size_t)n * DIM + kk * 32 + q * 8];
        }
    }
    {
        int row = t >> 4, c = (t & 15) * 8;
        if (xb) {
            *(i32x4*)&lx[row][c] = *(const i32x4*)&xb[(size_t)(m0 + row) * DIM + c];
        } else {
            f32x4 x0 = *(const f32x4*)&xf[(size_t)(m0 + row) * DIM + c];
            f32x4 x1 = *(const f32x4*)&xf[(size_t)(m0 + row) * DIM + c + 4];
            bf8 pk;
#pragma unroll
            for (int j = 0; j < 8; ++j) {
                float xv = (j < 4) ? x0[j] : x1[j - 4];
                pk[j] = f2bf(fmaxf((xv - smn[c + j]) * srv[c + j], 0.f));
            }
            *(bf8*)&lx[row][c] = pk;
        }
        *(i32x4*)&lp[row][c] = *(const i32x4*)&Pbf[(size_t)(m0 + row) * DIM + c];
    }
    if (t < 128) { sv1[t] = v1[t]; sv2[t] = v2[t]; }
    if (t < 16) { float r = rs[m0 + t]; rsL[t] = r; idL[t] = 1.f / (r + 1e-8f); }
    __syncthreads();
    if (t < 128) {
        int row = t >> 3, seg = t & 7;
        float id = idL[row];
        float s = 0.f;
#pragma unroll
        for (int j = 0; j < 16; ++j) {
            int c3 = seg * 16 + j;
            s += bf2f(lx[row][c3]) * sv1[c3] + bf2f(lp[row][c3]) * (sv2[c3] * id);
        }
        s += __shfl_xor(s, 1); s += __shfl_xor(s, 2); s += __shfl_xor(s, 4);
        if (seg == 0) {
            float sc = s + cc[0] + rsL[row] * cc[1] * id;
            sc = sc > 0.f ? sc : 0.2f * sc;
            coL[row] = 1.f / (1.f + __expf(-sc));
        }
    }
    f32x4 a1[2] = {{0.f, 0.f, 0.f, 0.f}, {0.f, 0.f, 0.f, 0.f}};
    f32x4 a2[2] = {{0.f, 0.f, 0.f, 0.f}, {0.f, 0.f, 0.f, 0.f}};
#pragma unroll
    for (int kk = 0; kk < 4; ++kk) {
        bf8 xa = *(bf8*)&lx[lr][kk * 32 + q * 8];
        bf8 pa = *(bf8*)&lp[lr][kk * 32 + q * 8];
#pragma unroll
        for (int nf = 0; nf < 2; ++nf) {
            a1[nf] = __builtin_amdgcn_mfma_f32_16x16x32_bf16(xa, b1[nf][kk], a1[nf], 0, 0, 0);
            a2[nf] = __builtin_amdgcn_mfma_f32_16x16x32_bf16(pa, b2[nf][kk], a2[nf], 0, 0, 0);
        }
    }
    __syncthreads();   // coL visible
    unsigned* aminS = aminC + (blockIdx.x & (NSHADOW - 1)) * DIM;
    unsigned* amaxS = amaxC + (blockIdx.x & (NSHADOW - 1)) * DIM;
#pragma unroll
    for (int nf = 0; nf < 2; ++nf) {
        int col = w * 32 + nf * 16 + lr;
        float u1v = u1[col], u2v = u2[col];
        float mnv = 1e30f, mxv = -1e30f;
#pragma unroll
        for (int r = 0; r < 4; ++r) {
            int row = q * 4 + r;
            float cf = coL[row] * idL[row];
            float v = a1[nf][r] + cf * a2[nf][r] + u1v + rsL[row] * cf * u2v;
            outw[(size_t)(m0 + row) * DIM + col] = v;
            mnv = fminf(mnv, v); mxv = fmaxf(mxv, v);
        }
        mnv = fminf(mnv, __shfl_xor(mnv, 16)); mnv = fminf(mnv, __shfl_xor(mnv, 32));
        mxv = fmaxf(mxv, __shfl_xor(mxv, 16)); mxv = fmaxf(mxv, __shfl_xor(mxv, 32));
        if (l < 16) {
            atomicMin(&aminS[col], fkey(mnv));
            atomicMax(&amaxS[col], fkey(mxv));
        }
    }
}

// ============ k_fin: reduce last head's shadow minmax, normalize + relu -> d_out ============
__global__ __launch_bounds__(256) void k_fin(const float* __restrict__ outp,
        const unsigned* __restrict__ amin, const unsigned* __restrict__ amax,
        float* __restrict__ dst) {
    __shared__ float smn[128], srv[128];
    int t = threadIdx.x;
    if (t < 128) {
        unsigned kmn = 0xFFFFFFFFu, kmx = 0u;
#pragma unroll
        for (int p = 0; p < NSHADOW; ++p) {
            kmn = min(kmn, amin[p * DIM + t]);
            kmx = max(kmx, amax[p * DIM + t]);
        }
        float mn = fdec(kmn);
        smn[t] = mn;
        srv[t] = 1.f / (fdec(kmx) - mn + 1e-8f);
    }
    __syncthreads();
#pragma unroll
    for (int i = 0; i < 2; ++i) {
        int idx = blockIdx.x * 256 + t + i * 131072;
        f32x4 v = *((const f32x4*)outp + idx);
        int c0 = (idx & 31) * 4;
#pragma unroll
        for (int j = 0; j < 4; ++j) v[j] = fmaxf((v[j] - smn[c0 + j]) * srv[c0 + j], 0.f);
        *((f32x4*)dst + idx) = v;
    }
}

extern "C" void kernel_launch(void* const* d_in, const int* in_sizes, int n_in,
                              void* d_out, int out_size, void* d_ws, size_t ws_size,
                              hipStream_t stream) {
    const float* nodef = (const float*)d_in[0];
    const float* inc   = (const float*)d_in[1];
    const float* ef    = (const float*)d_in[2];
    const float* Wn    = (const float*)d_in[3];
    const float* bn    = (const float*)d_in[4];
    const float* We    = (const float*)d_in[5];
    const float* be    = (const float*)d_in[6];
    const float* Wa    = (const float*)d_in[7];
    const float* ba    = (const float*)d_in[8];
    const float* Wo    = (const float*)d_in[9];
    const float* bo    = (const float*)d_in[10];

    char* ws = (char*)d_ws;
    float*    outp  = (float*)(ws);                 // 4 MB
    short*    Pbf   = (short*)(ws + 4194304);       // 2 MB
    short*    xb    = (short*)(ws + 6291456);       // 2 MB
    short*    efB   = (short*)(ws + 8388608);       // 1 MB (swizzled)
    short*    A1T   = (short*)(ws + 9437184);       // 128 KB
    short*    A2T   = (short*)(ws + 9568256);       // 128 KB
    float*    rs    = (float*)(ws + 9699328);       // 32 KB
    float*    v1    = (float*)(ws + 9732096);
    float*    v2    = (float*)(ws + 9734144);
    float*    u1    = (float*)(ws + 9736192);
    float*    u2    = (float*)(ws + 9738240);
    float*    cc    = (float*)(ws + 9740288);
    unsigned* amin  = (unsigned*)(ws + 9742336);    // NHEADS*NSHADOW*128 = 16 KB
    unsigned* amax  = (unsigned*)(ws + 9758720);    // 16 KB

    hipLaunchKernelGGL(k_init, dim3(512), dim3(256), 0, stream,
                       ef, efB, nodef, xb, Wn, We, Wo, Wa, bn, be, ba, bo,
                       A1T, A2T, v1, v2, u1, u2, cc, amin, amax);
    hipLaunchKernelGGL(k_pgemm, dim3(256), dim3(512), 0, stream, inc, efB, Pbf, rs);

    for (int h = 0; h < NHEADS; ++h) {
        hipLaunchKernelGGL(k_out, dim3(512), dim3(256), 0, stream,
                           (h == 0) ? xb : (const short*)nullptr,
                           (h == 0) ? (const float*)nullptr : outp,
                           (h == 0) ? (const unsigned*)nullptr : amin + (h - 1) * NSHADOW * DIM,
                           (h == 0) ? (const unsigned*)nullptr : amax + (h - 1) * NSHADOW * DIM,
                           Pbf, rs,
                           A1T + (size_t)h * DIM * DIM, A2T + (size_t)h * DIM * DIM,
                           v1 + h * DIM, v2 + h * DIM, cc + h * 2,
                           u1 + h * DIM, u2 + h * DIM,
                           amin + h * NSHADOW * DIM, amax + h * NSHADOW * DIM, outp);
    }
    hipLaunchKernelGGL(k_fin, dim3(512), dim3(256), 0, stream, outp,
                       amin + 3 * NSHADOW * DIM, amax + 3 * NSHADOW * DIM, (float*)d_out);
}